// Round 1
// baseline (409.369 us; speedup 1.0000x reference)
//
#include <hip/hip_runtime.h>
#include <hip/hip_bf16.h>

typedef __attribute__((ext_vector_type(8))) __bf16 bf16x8;
typedef __attribute__((ext_vector_type(4))) float f32x4;

#define BM 128
#define BN 128
#define BK 32
#define GEMM_THREADS 256

#define GLOBAL_CPTR(x) ((__attribute__((address_space(1))) const void*)(x))
#define LDS_PTR(x)     ((__attribute__((address_space(3))) void*)(x))

// ---------------------------------------------------------------------------
// MXFP4 fake-quantize: fp32 -> bf16 (exact representation of dequant values)
// One 32-elem MXFP block per 8-lane group; 4 floats per lane (float4 load).
// ---------------------------------------------------------------------------
__global__ __launch_bounds__(256) void mxfp4_quant_kernel(
    const float* __restrict__ in, ushort* __restrict__ out, long long n) {
  long long base = ((long long)blockIdx.x * 256 + threadIdx.x) * 4;
  if (base >= n) return;

  float4 v = *reinterpret_cast<const float4*>(in + base);
  float am = fmaxf(fmaxf(fabsf(v.x), fabsf(v.y)), fmaxf(fabsf(v.z), fabsf(v.w)));
  // reduce amax across the 8-lane group (covers 32 elements = one MXFP block)
  am = fmaxf(am, __shfl_xor(am, 1, 64));
  am = fmaxf(am, __shfl_xor(am, 2, 64));
  am = fmaxf(am, __shfl_xor(am, 4, 64));

  float safe = am > 0.f ? am : 1.f;
  int se = ilogbf(safe) - 2;           // floor(log2(amax)) - E2M1_EMAX
  float scale = ldexpf(1.f, se);
  float inv   = ldexpf(1.f, -se);

  float vv[4] = {v.x, v.y, v.z, v.w};
  ushort o16[4];
#pragma unroll
  for (int j = 0; j < 4; ++j) {
    float val = vv[j] * inv;                 // exact (power-of-2)
    float av = fabsf(val);
    float avc = fmaxf(av, 9.765625e-4f);     // 2^-10 floor, guarantees normal fp32
    int e = (int)((__float_as_uint(avc) >> 23) & 0xFF) - 127;  // floor(log2)
    e = e < 0 ? 0 : (e > 2 ? 2 : e);
    float step  = ldexpf(1.f, e - 1);
    float istep = ldexpf(1.f, 1 - e);
    float q = rintf(av * istep) * step;      // round-half-to-even, exact scaling
    q = fminf(q, 6.f);
    float r = copysignf(q * scale, val);     // exact in bf16
    __hip_bfloat16 b = __float2bfloat16(r);
    o16[j] = *reinterpret_cast<ushort*>(&b);
  }
  ushort4 packed = make_ushort4(o16[0], o16[1], o16[2], o16[3]);
  *reinterpret_cast<ushort4*>(out + base) = packed;
}

// ---------------------------------------------------------------------------
// bf16 GEMM: C[M][N] = A[M][K] * B[N][K]^T + bias[N]   (m97 structure)
// 128x128 tile, BK=32, 4 waves (2x2), 4x4 16x16x32 MFMA frags per wave,
// global_load_lds width-16 staging, 2 barriers per K-step.
// ---------------------------------------------------------------------------
__global__ __launch_bounds__(GEMM_THREADS) void mxfp_gemm_kernel(
    const ushort* __restrict__ A, const ushort* __restrict__ B,
    const float* __restrict__ bias, float* __restrict__ C,
    int M, int N, int K) {
  __shared__ ushort As[BM * BK];  // 8 KB
  __shared__ ushort Bs[BN * BK];  // 8 KB

  const int tid = threadIdx.x;
  const int wid = tid >> 6;
  const int lane = tid & 63;

  // XCD-aware swizzle (grid count is a multiple of 8 here: 64*32 = 2048)
  const int nwg = gridDim.x;
  const int cpx = nwg >> 3;
  const int bid = blockIdx.x;
  const int swz = (bid & 7) * cpx + (bid >> 3);
  const int nbn = N / BN;
  const int bm = swz / nbn;
  const int bn = swz % nbn;

  const int wm = wid >> 1;  // 0..1
  const int wn = wid & 1;   // 0..1

  f32x4 acc[4][4] = {};

  // staging geometry: 8 chunks of 16 rows each per tile; wave w does chunks
  // {2w, 2w+1}. Within a chunk: lane l -> row l>>2, col (l&3)*8 (16B).
  const long long Abase = (long long)(bm * BM) * K;
  const long long Bbase = (long long)(bn * BN) * K;
  const int r0 = wid * 32 + (lane >> 2);  // chunk 2w rows [32w .. 32w+15]
  const int cofs = (lane & 3) * 8;

  const int frow = lane & 15;
  const int kofs = (lane >> 4) * 8;

  for (int kt = 0; kt < K; kt += BK) {
    // ---- stage A (2 insts) + B (2 insts) per wave ----
    __builtin_amdgcn_global_load_lds(
        GLOBAL_CPTR(A + Abase + (long long)r0 * K + kt + cofs),
        LDS_PTR(As + wid * 32 * BK), 16, 0, 0);
    __builtin_amdgcn_global_load_lds(
        GLOBAL_CPTR(A + Abase + (long long)(r0 + 16) * K + kt + cofs),
        LDS_PTR(As + (wid * 32 + 16) * BK), 16, 0, 0);
    __builtin_amdgcn_global_load_lds(
        GLOBAL_CPTR(B + Bbase + (long long)r0 * K + kt + cofs),
        LDS_PTR(Bs + wid * 32 * BK), 16, 0, 0);
    __builtin_amdgcn_global_load_lds(
        GLOBAL_CPTR(B + Bbase + (long long)(r0 + 16) * K + kt + cofs),
        LDS_PTR(Bs + (wid * 32 + 16) * BK), 16, 0, 0);

    __syncthreads();  // compiler emits vmcnt(0) drain before barrier

    // ---- LDS -> frags, 8x ds_read_b128 ----
    bf16x8 af[4], bfv[4];
#pragma unroll
    for (int i = 0; i < 4; ++i) {
      af[i]  = *reinterpret_cast<const bf16x8*>(As + (wm * 64 + i * 16 + frow) * BK + kofs);
      bfv[i] = *reinterpret_cast<const bf16x8*>(Bs + (wn * 64 + i * 16 + frow) * BK + kofs);
    }

    // ---- 16 MFMA ----
#pragma unroll
    for (int i = 0; i < 4; ++i)
#pragma unroll
      for (int j = 0; j < 4; ++j)
        acc[i][j] = __builtin_amdgcn_mfma_f32_16x16x32_bf16(af[i], bfv[j], acc[i][j], 0, 0, 0);

    __syncthreads();
  }

  // ---- epilogue: C/D layout col=lane&15, row=(lane>>4)*4+reg ----
  const int colb = bn * BN + wn * 64 + (lane & 15);
  const int rowb = bm * BM + wm * 64 + (lane >> 4) * 4;
#pragma unroll
  for (int j = 0; j < 4; ++j) {
    const float bv = bias[colb + j * 16];
#pragma unroll
    for (int i = 0; i < 4; ++i) {
#pragma unroll
      for (int r = 0; r < 4; ++r) {
        C[(long long)(rowb + i * 16 + r) * N + (colb + j * 16)] = acc[i][j][r] + bv;
      }
    }
  }
}

// ---------------------------------------------------------------------------
extern "C" void kernel_launch(void* const* d_in, const int* in_sizes, int n_in,
                              void* d_out, int out_size, void* d_ws, size_t ws_size,
                              hipStream_t stream) {
  const float* x    = (const float*)d_in[0];  // [B,S,K] = [M,K]
  const float* w    = (const float*)d_in[1];  // [N,K]
  const float* bias = (const float*)d_in[2];  // [N]
  float* out = (float*)d_out;

  const int N = in_sizes[2];
  const int K = in_sizes[1] / N;
  const int M = (int)((long long)in_sizes[0] / K);

  ushort* xq = (ushort*)d_ws;                       // M*K bf16
  ushort* wq = xq + (size_t)M * K;                  // N*K bf16

  const long long nx = (long long)M * K;
  const long long nw = (long long)N * K;

  mxfp4_quant_kernel<<<dim3((unsigned)(nx / 1024)), dim3(256), 0, stream>>>(x, xq, nx);
  mxfp4_quant_kernel<<<dim3((unsigned)(nw / 1024)), dim3(256), 0, stream>>>(w, wq, nw);

  dim3 grid((M / BM) * (N / BN));
  mxfp_gemm_kernel<<<grid, dim3(GEMM_THREADS), 0, stream>>>(xq, wq, bias, out, M, N, K);
}

// Round 2
// 267.993 us; speedup vs baseline: 1.5275x; 1.5275x over previous
//
#include <hip/hip_runtime.h>
#include <hip/hip_bf16.h>

typedef __attribute__((ext_vector_type(8))) __bf16 bf16x8;
typedef __attribute__((ext_vector_type(4))) float f32x4;

#define GLOBAL_CPTR(x) ((__attribute__((address_space(1))) const void*)(x))
#define LDS_PTR(x)     ((__attribute__((address_space(3))) void*)(x))

// ---------------------------------------------------------------------------
// MXFP4 fake-quantize: fp32 -> bf16 (exact representation of dequant values)
// One 32-elem MXFP block per 8-lane group; 4 floats per lane (float4 load).
// ---------------------------------------------------------------------------
__global__ __launch_bounds__(256) void mxfp4_quant_kernel(
    const float* __restrict__ in, ushort* __restrict__ out, long long n) {
  long long base = ((long long)blockIdx.x * 256 + threadIdx.x) * 4;
  if (base >= n) return;

  float4 v = *reinterpret_cast<const float4*>(in + base);
  float am = fmaxf(fmaxf(fabsf(v.x), fabsf(v.y)), fmaxf(fabsf(v.z), fabsf(v.w)));
  am = fmaxf(am, __shfl_xor(am, 1, 64));
  am = fmaxf(am, __shfl_xor(am, 2, 64));
  am = fmaxf(am, __shfl_xor(am, 4, 64));

  float safe = am > 0.f ? am : 1.f;
  int se = ilogbf(safe) - 2;           // floor(log2(amax)) - E2M1_EMAX
  float scale = ldexpf(1.f, se);
  float inv   = ldexpf(1.f, -se);

  float vv[4] = {v.x, v.y, v.z, v.w};
  ushort o16[4];
#pragma unroll
  for (int j = 0; j < 4; ++j) {
    float val = vv[j] * inv;                 // exact (power-of-2)
    float av = fabsf(val);
    float avc = fmaxf(av, 9.765625e-4f);     // 2^-10 floor
    int e = (int)((__float_as_uint(avc) >> 23) & 0xFF) - 127;  // floor(log2)
    e = e < 0 ? 0 : (e > 2 ? 2 : e);
    float step  = ldexpf(1.f, e - 1);
    float istep = ldexpf(1.f, 1 - e);
    float q = rintf(av * istep) * step;      // round-half-to-even
    q = fminf(q, 6.f);
    float r = copysignf(q * scale, val);     // exact in bf16
    __hip_bfloat16 b = __float2bfloat16(r);
    o16[j] = *reinterpret_cast<ushort*>(&b);
  }
  ushort4 packed = make_ushort4(o16[0], o16[1], o16[2], o16[3]);
  *reinterpret_cast<ushort4*>(out + base) = packed;
}

// ---------------------------------------------------------------------------
// 256x256 8-phase bf16 GEMM: C[M][N] = A[M][K]*B[N][K]^T + bias[N]
// 8 waves (2Mx4N), BK=64, 128KiB LDS (2 dbuf x (A+B) x 2 halves),
// st_16x32 LDS swizzle, counted vmcnt(4), setprio around MFMA clusters.
// ---------------------------------------------------------------------------
#define BM 256
#define BN 256
#define BK 64
#define NTHR 512

__global__ __launch_bounds__(NTHR, 2) void mxfp_gemm_kernel(
    const ushort* __restrict__ A, const ushort* __restrict__ B,
    const float* __restrict__ bias, float* __restrict__ C,
    int M, int N, int K) {
  // layout (ushort offsets): buf b: b*32768; A at +0, B at +16384;
  // half h: +h*8192; rowblock (16 rows): 1024; col-subtile (32 cols): 512;
  // row-in-subtile: 32; swizzle: col-group-of-8 XOR'd by 16 when (row&8).
  __shared__ ushort lds[65536];  // 128 KiB

  const int tid = threadIdx.x;
  const int l   = tid & 63;
  const int wid = tid >> 6;
  const int wm  = wid >> 2;  // 0..1
  const int wn  = wid & 3;   // 0..3

  const int nwg = gridDim.x;       // 512 (divisible by 8)
  const int bid = blockIdx.x;
  const int swz = (bid & 7) * (nwg >> 3) + (bid >> 3);
  const int nbn = N / BN;
  const int bm  = swz / nbn;
  const int bn  = swz % nbn;

  // staging source geometry (inverse-swizzled global source, linear LDS dest)
  const int rowInHalf0 = ((tid >> 7) << 4) + ((tid >> 2) & 15);
  const int colInTile  = (((tid >> 6) & 1) << 5) +
                         (((tid & 3) << 3) ^ ((tid & 32) ? 16 : 0));
  const ushort* aBase = A + (size_t)(bm * BM + rowInHalf0) * K + colInTile;
  const ushort* bBase = B + (size_t)(bn * BN + rowInHalf0) * K + colInTile;
  const int ldsW = wid << 9;  // wave-uniform stage dest offset (ushorts)

  // swizzled per-lane ds_read offset
  const int laneRd = ((l & 15) << 5) + (((l >> 4) << 3) ^ ((l & 8) ? 16 : 0));
  const int aRd = (wm << 13) + laneRd;
  const int bRd = 16384 + ((wn >> 1) << 13) + ((wn & 1) << 12) + laneRd;

  f32x4 acc[8][4] = {};
  bf16x8 bfr[4][2], af[2][2];

#define STAGE(BASE, BUFO, OPO, H, KT)                                           \
  do {                                                                          \
    const ushort* _s = (BASE) + (size_t)(H) * 128 * K + (KT);                   \
    __builtin_amdgcn_global_load_lds(GLOBAL_CPTR(_s),                           \
        LDS_PTR(lds + (BUFO) + (OPO) + (H) * 8192 + ldsW), 16, 0, 0);           \
    __builtin_amdgcn_global_load_lds(GLOBAL_CPTR(_s + (size_t)64 * K),          \
        LDS_PTR(lds + (BUFO) + (OPO) + (H) * 8192 + 4096 + ldsW), 16, 0, 0);    \
  } while (0)

#define LDB(BUFO)                                                               \
  do {                                                                          \
    _Pragma("unroll") for (int j = 0; j < 4; ++j)                               \
      _Pragma("unroll") for (int s = 0; s < 2; ++s)                             \
        bfr[j][s] = *(const bf16x8*)(lds + (BUFO) + bRd + (j << 10) + (s << 9));\
  } while (0)

#define LDA2(BUFO, Q)                                                           \
  do {                                                                          \
    _Pragma("unroll") for (int ii = 0; ii < 2; ++ii)                            \
      _Pragma("unroll") for (int s = 0; s < 2; ++s)                             \
        af[ii][s] = *(const bf16x8*)(lds + (BUFO) + aRd +                       \
                                     ((((Q) << 1) + ii) << 10) + (s << 9));     \
  } while (0)

#define MFMAQ(Q)                                                                \
  do {                                                                          \
    _Pragma("unroll") for (int s = 0; s < 2; ++s)                               \
      _Pragma("unroll") for (int ii = 0; ii < 2; ++ii)                          \
        _Pragma("unroll") for (int j = 0; j < 4; ++j)                           \
          acc[((Q) << 1) + ii][j] = __builtin_amdgcn_mfma_f32_16x16x32_bf16(    \
              af[ii][s], bfr[j][s], acc[((Q) << 1) + ii][j], 0, 0, 0);          \
  } while (0)

#define PH(BUFO, Q, FIRST, STG, VM)                                             \
  do {                                                                          \
    if (FIRST) LDB(BUFO);                                                       \
    LDA2(BUFO, Q);                                                              \
    STG;                                                                        \
    if (FIRST) asm volatile("s_waitcnt lgkmcnt(8)" ::: "memory");               \
    __builtin_amdgcn_s_barrier();                                               \
    asm volatile("s_waitcnt lgkmcnt(0)" ::: "memory");                          \
    __builtin_amdgcn_s_setprio(1);                                              \
    MFMAQ(Q);                                                                   \
    __builtin_amdgcn_s_setprio(0);                                              \
    if (VM) asm volatile("s_waitcnt vmcnt(4)" ::: "memory");                    \
    __builtin_amdgcn_s_barrier();                                               \
  } while (0)

  // prologue: tile0 B+A into buf0, tile1 B into buf1 (12 loads in flight)
  STAGE(bBase, 0, 16384, 0, 0);
  STAGE(bBase, 0, 16384, 1, 0);
  STAGE(aBase, 0, 0, 0, 0);
  STAGE(aBase, 0, 0, 1, 0);
  STAGE(bBase, 32768, 16384, 0, BK);
  STAGE(bBase, 32768, 16384, 1, BK);
  asm volatile("s_waitcnt vmcnt(4)" ::: "memory");  // tile0 fully landed
  __builtin_amdgcn_s_barrier();

  const int NKT = K >> 6;  // 64 K-tiles
  for (int it = 0; it < (NKT >> 1); ++it) {
    const int t = it << 1;
    const int ktA1 = (t + 1) << 6;                               // live
    const int kt2  = ((t + 2 < NKT) ? (t + 2) : (NKT - 1)) << 6; // clamp->dead
    const int kt3  = ((t + 3 < NKT) ? (t + 3) : (NKT - 1)) << 6; // clamp->dead
    // K-tile t (buf0): stages = A(buf1)[t+1] h0,h1; B(buf0)[t+2] h0,h1
    PH(0,     0, 1, STAGE(aBase, 32768, 0,     0, ktA1), 0);
    PH(0,     1, 0, STAGE(aBase, 32768, 0,     1, ktA1), 0);
    PH(0,     2, 0, STAGE(bBase, 0,     16384, 0, kt2),  0);
    PH(0,     3, 0, STAGE(bBase, 0,     16384, 1, kt2),  1);
    // K-tile t+1 (buf1): stages = A(buf0)[t+2] h0,h1; B(buf1)[t+3] h0,h1
    PH(32768, 0, 1, STAGE(aBase, 0,     0,     0, kt2),  0);
    PH(32768, 1, 0, STAGE(aBase, 0,     0,     1, kt2),  0);
    PH(32768, 2, 0, STAGE(bBase, 32768, 16384, 0, kt3),  0);
    PH(32768, 3, 0, STAGE(bBase, 32768, 16384, 1, kt3),  1);
  }
  asm volatile("s_waitcnt vmcnt(0)" ::: "memory");  // drain dead tail stages

  // epilogue: C/D layout col=lane&15, row=(lane>>4)*4+reg (m89-verified)
  const int colb = bn * BN + wn * 64 + (l & 15);
  const long long rowb = (long long)bm * BM + wm * 128 + ((l >> 4) << 2);
#pragma unroll
  for (int j = 0; j < 4; ++j) {
    const float bv = bias[colb + j * 16];
#pragma unroll
    for (int i = 0; i < 8; ++i) {
#pragma unroll
      for (int r = 0; r < 4; ++r) {
        C[(rowb + i * 16 + r) * N + (colb + j * 16)] = acc[i][j][r] + bv;
      }
    }
  }
}

// ---------------------------------------------------------------------------
extern "C" void kernel_launch(void* const* d_in, const int* in_sizes, int n_in,
                              void* d_out, int out_size, void* d_ws, size_t ws_size,
                              hipStream_t stream) {
  const float* x    = (const float*)d_in[0];  // [B,S,K] = [M,K]
  const float* w    = (const float*)d_in[1];  // [N,K]
  const float* bias = (const float*)d_in[2];  // [N]
  float* out = (float*)d_out;

  const int N = in_sizes[2];
  const int K = in_sizes[1] / N;
  const int M = (int)((long long)in_sizes[0] / K);

  ushort* xq = (ushort*)d_ws;                       // M*K bf16
  ushort* wq = xq + (size_t)M * K;                  // N*K bf16

  const long long nx = (long long)M * K;
  const long long nw = (long long)N * K;

  mxfp4_quant_kernel<<<dim3((unsigned)(nx / 1024)), dim3(256), 0, stream>>>(x, xq, nx);
  mxfp4_quant_kernel<<<dim3((unsigned)(nw / 1024)), dim3(256), 0, stream>>>(w, wq, nw);

  dim3 grid((M / BM) * (N / BN));
  mxfp_gemm_kernel<<<grid, dim3(NTHR), 0, stream>>>(xq, wq, bias, out, M, N, K);
}

// Round 3
// 267.754 us; speedup vs baseline: 1.5289x; 1.0009x over previous
//
#include <hip/hip_runtime.h>
#include <hip/hip_bf16.h>

typedef __attribute__((ext_vector_type(8))) __bf16 bf16x8;
typedef __attribute__((ext_vector_type(4))) float f32x4;

#define GLOBAL_CPTR(x) ((__attribute__((address_space(1))) const void*)(x))
#define LDS_PTR(x)     ((__attribute__((address_space(3))) void*)(x))

// ---------------------------------------------------------------------------
// MXFP4 fake-quantize: fp32 -> bf16 (exact representation of dequant values)
// ---------------------------------------------------------------------------
__global__ __launch_bounds__(256) void mxfp4_quant_kernel(
    const float* __restrict__ in, ushort* __restrict__ out, long long n) {
  long long base = ((long long)blockIdx.x * 256 + threadIdx.x) * 4;
  if (base >= n) return;

  float4 v = *reinterpret_cast<const float4*>(in + base);
  float am = fmaxf(fmaxf(fabsf(v.x), fabsf(v.y)), fmaxf(fabsf(v.z), fabsf(v.w)));
  am = fmaxf(am, __shfl_xor(am, 1, 64));
  am = fmaxf(am, __shfl_xor(am, 2, 64));
  am = fmaxf(am, __shfl_xor(am, 4, 64));

  float safe = am > 0.f ? am : 1.f;
  int se = ilogbf(safe) - 2;           // floor(log2(amax)) - E2M1_EMAX
  float scale = ldexpf(1.f, se);
  float inv   = ldexpf(1.f, -se);

  float vv[4] = {v.x, v.y, v.z, v.w};
  ushort o16[4];
#pragma unroll
  for (int j = 0; j < 4; ++j) {
    float val = vv[j] * inv;                 // exact (power-of-2)
    float av = fabsf(val);
    float avc = fmaxf(av, 9.765625e-4f);     // 2^-10 floor
    int e = (int)((__float_as_uint(avc) >> 23) & 0xFF) - 127;  // floor(log2)
    e = e < 0 ? 0 : (e > 2 ? 2 : e);
    float step  = ldexpf(1.f, e - 1);
    float istep = ldexpf(1.f, 1 - e);
    float q = rintf(av * istep) * step;      // round-half-to-even
    q = fminf(q, 6.f);
    float r = copysignf(q * scale, val);     // exact in bf16
    __hip_bfloat16 b = __float2bfloat16(r);
    o16[j] = *reinterpret_cast<ushort*>(&b);
  }
  ushort4 packed = make_ushort4(o16[0], o16[1], o16[2], o16[3]);
  *reinterpret_cast<ushort4*>(out + base) = packed;
}

// ---------------------------------------------------------------------------
// 256x256 8-phase bf16 GEMM with cross-phase pipelined LDS->reg loads.
// C[M][N] = A[M][K]*B[N][K]^T + bias[N]
// 8 waves (2Mx4N), BK=64, 128KiB LDS dbuf, st_16x32 swizzle, counted vmcnt(4),
// setprio around MFMA clusters. Phase p issues ds_reads for phase p+1's
// fragments (af_a/af_b ping-pong); compiler emits counted lgkmcnt at use.
// ---------------------------------------------------------------------------
#define BM 256
#define BN 256
#define BK 64
#define NTHR 512

__global__ __launch_bounds__(NTHR, 2) void mxfp_gemm_kernel(
    const ushort* __restrict__ A, const ushort* __restrict__ B,
    const float* __restrict__ bias, float* __restrict__ C,
    int M, int N, int K) {
  __shared__ ushort lds[65536];  // 128 KiB

  const int tid = threadIdx.x;
  const int l   = tid & 63;
  const int wid = tid >> 6;
  const int wm  = wid >> 2;  // 0..1
  const int wn  = wid & 3;   // 0..3

  const int nwg = gridDim.x;       // multiple of 8
  const int bid = blockIdx.x;
  const int swz = (bid & 7) * (nwg >> 3) + (bid >> 3);
  const int nbn = N / BN;
  const int bm  = swz / nbn;
  const int bn  = swz % nbn;

  // staging source geometry (inverse-swizzled global source, linear LDS dest)
  const int rowInHalf0 = ((tid >> 7) << 4) + ((tid >> 2) & 15);
  const int colInTile  = (((tid >> 6) & 1) << 5) +
                         (((tid & 3) << 3) ^ ((tid & 32) ? 16 : 0));
  const ushort* aBase = A + (size_t)(bm * BM + rowInHalf0) * K + colInTile;
  const ushort* bBase = B + (size_t)(bn * BN + rowInHalf0) * K + colInTile;
  const int ldsW = wid << 9;  // wave-uniform stage dest offset (ushorts)

  // swizzled per-lane ds_read offset
  const int laneRd = ((l & 15) << 5) + (((l >> 4) << 3) ^ ((l & 8) ? 16 : 0));
  const int aRd = (wm << 13) + laneRd;
  const int bRd = 16384 + ((wn >> 1) << 13) + ((wn & 1) << 12) + laneRd;

  f32x4 acc[8][4] = {};
  bf16x8 bfr[4][2];        // B frags, whole K-tile (loaded at P1)
  bf16x8 af_a[2][2];       // A frag set A (quadrants 0,2)
  bf16x8 af_b[2][2];       // A frag set B (quadrants 1,3)

#define STAGE(BASE, BUFO, OPO, H, KT)                                           \
  do {                                                                          \
    const ushort* _s = (BASE) + (size_t)(H) * 128 * K + (KT);                   \
    __builtin_amdgcn_global_load_lds(GLOBAL_CPTR(_s),                           \
        LDS_PTR(lds + (BUFO) + (OPO) + (H) * 8192 + ldsW), 16, 0, 0);           \
    __builtin_amdgcn_global_load_lds(GLOBAL_CPTR(_s + (size_t)64 * K),          \
        LDS_PTR(lds + (BUFO) + (OPO) + (H) * 8192 + 4096 + ldsW), 16, 0, 0);    \
  } while (0)

#define LDB8(BUFO)                                                              \
  do {                                                                          \
    _Pragma("unroll") for (int j = 0; j < 4; ++j)                               \
      _Pragma("unroll") for (int s = 0; s < 2; ++s)                             \
        bfr[j][s] = *(const bf16x8*)(lds + (BUFO) + bRd + (j << 10) + (s << 9));\
  } while (0)

#define LDA4(SET, BUFO, Q)                                                      \
  do {                                                                          \
    _Pragma("unroll") for (int ii = 0; ii < 2; ++ii)                            \
      _Pragma("unroll") for (int s = 0; s < 2; ++s)                             \
        SET[ii][s] = *(const bf16x8*)(lds + (BUFO) + aRd +                      \
                                      ((((Q) << 1) + ii) << 10) + (s << 9));    \
  } while (0)

#define RD_P1(BUFO)                                                             \
  do { LDA4(af_a, BUFO, 0); LDB8(BUFO); LDA4(af_b, BUFO, 1); } while (0)

#define MFMAQ(SET, Q)                                                           \
  do {                                                                          \
    _Pragma("unroll") for (int s = 0; s < 2; ++s)                               \
      _Pragma("unroll") for (int ii = 0; ii < 2; ++ii)                          \
        _Pragma("unroll") for (int j = 0; j < 4; ++j)                           \
          acc[((Q) << 1) + ii][j] = __builtin_amdgcn_mfma_f32_16x16x32_bf16(    \
              SET[ii][s], bfr[j][s], acc[((Q) << 1) + ii][j], 0, 0, 0);         \
  } while (0)

// Phase: issue next-phase ds_reads (RDS), issue staging, barrier, MFMA on
// fragments loaded LAST phase (compiler inserts counted lgkmcnt at use).
#define PH(RDS, SET, Q, STG, VM)                                                \
  do {                                                                          \
    RDS;                                                                        \
    STG;                                                                        \
    __builtin_amdgcn_s_barrier();                                               \
    asm volatile("" ::: "memory");                                              \
    __builtin_amdgcn_s_setprio(1);                                              \
    MFMAQ(SET, Q);                                                              \
    __builtin_amdgcn_s_setprio(0);                                              \
    asm volatile("" ::: "memory");                                              \
    if (VM) asm volatile("s_waitcnt vmcnt(4)" ::: "memory");                    \
    __builtin_amdgcn_s_barrier();                                               \
    asm volatile("" ::: "memory");                                              \
  } while (0)

  // prologue: tile0 B+A into buf0, tile1 B into buf1 (12 loads in flight)
  STAGE(bBase, 0, 16384, 0, 0);
  STAGE(bBase, 0, 16384, 1, 0);
  STAGE(aBase, 0, 0, 0, 0);
  STAGE(aBase, 0, 0, 1, 0);
  STAGE(bBase, 32768, 16384, 0, BK);
  STAGE(bBase, 32768, 16384, 1, BK);
  asm volatile("s_waitcnt vmcnt(4)" ::: "memory");  // tile0 fully landed
  __builtin_amdgcn_s_barrier();
  asm volatile("" ::: "memory");

  const int NKT = K >> 6;
  for (int it = 0; it < (NKT >> 1); ++it) {
    const int t = it << 1;
    const int ktA1 = (t + 1) << 6;                               // live
    const int kt2  = ((t + 2 < NKT) ? (t + 2) : (NKT - 1)) << 6; // clamp->dead
    const int kt3  = ((t + 3 < NKT) ? (t + 3) : (NKT - 1)) << 6; // clamp->dead
    // K-tile t (buf0): stages = A(buf1)[t+1] h0,h1; B(buf0)[t+2] h0,h1
    PH(RD_P1(0),               af_a, 0, STAGE(aBase, 32768, 0,     0, ktA1), 0);
    PH(LDA4(af_a, 0, 2),       af_b, 1, STAGE(aBase, 32768, 0,     1, ktA1), 0);
    PH(LDA4(af_b, 0, 3),       af_a, 2, STAGE(bBase, 0,     16384, 0, kt2),  0);
    PH((void)0,                af_b, 3, STAGE(bBase, 0,     16384, 1, kt2),  1);
    // K-tile t+1 (buf1): stages = A(buf0)[t+2] h0,h1; B(buf1)[t+3] h0,h1
    PH(RD_P1(32768),           af_a, 0, STAGE(aBase, 0,     0,     0, kt2),  0);
    PH(LDA4(af_a, 32768, 2),   af_b, 1, STAGE(aBase, 0,     0,     1, kt2),  0);
    PH(LDA4(af_b, 32768, 3),   af_a, 2, STAGE(bBase, 32768, 16384, 0, kt3),  0);
    PH((void)0,                af_b, 3, STAGE(bBase, 32768, 16384, 1, kt3),  1);
  }
  asm volatile("s_waitcnt vmcnt(0)" ::: "memory");  // drain dead tail stages

  // epilogue: C/D layout col=lane&15, row=(lane>>4)*4+reg (m89-verified)
  const int colb = bn * BN + wn * 64 + (l & 15);
  const long long rowb = (long long)bm * BM + wm * 128 + ((l >> 4) << 2);
#pragma unroll
  for (int j = 0; j < 4; ++j) {
    const float bv = bias[colb + j * 16];
#pragma unroll
    for (int i = 0; i < 8; ++i) {
#pragma unroll
      for (int r = 0; r < 4; ++r) {
        C[(rowb + i * 16 + r) * N + (colb + j * 16)] = acc[i][j][r] + bv;
      }
    }
  }
}

// ---------------------------------------------------------------------------
extern "C" void kernel_launch(void* const* d_in, const int* in_sizes, int n_in,
                              void* d_out, int out_size, void* d_ws, size_t ws_size,
                              hipStream_t stream) {
  const float* x    = (const float*)d_in[0];  // [B,S,K] = [M,K]
  const float* w    = (const float*)d_in[1];  // [N,K]
  const float* bias = (const float*)d_in[2];  // [N]
  float* out = (float*)d_out;

  const int N = in_sizes[2];
  const int K = in_sizes[1] / N;
  const int M = (int)((long long)in_sizes[0] / K);

  ushort* xq = (ushort*)d_ws;                       // M*K bf16
  ushort* wq = xq + (size_t)M * K;                  // N*K bf16

  const long long nx = (long long)M * K;
  const long long nw = (long long)N * K;

  mxfp4_quant_kernel<<<dim3((unsigned)(nx / 1024)), dim3(256), 0, stream>>>(x, xq, nx);
  mxfp4_quant_kernel<<<dim3((unsigned)(nw / 1024)), dim3(256), 0, stream>>>(w, wq, nw);

  dim3 grid((M / BM) * (N / BN));
  mxfp_gemm_kernel<<<grid, dim3(NTHR), 0, stream>>>(xq, wq, bias, out, M, N, K);
}